// Round 5
// baseline (672.828 us; speedup 1.0000x reference)
//
#include <hip/hip_runtime.h>

#define NB 32      // batch
#define NJ 8192    // h*w*Nin
#define NC 10      // NUM_CAPS
#define CL 16      // CAP_LEN
#define KK 160     // NC*CL
#define JT 16      // j per block
#define BB 8       // batches per block
#define NTH 256    // 16 jr x 16 c   (t = jr*16 + c)
#define NPART (NJ / JT)   // 512 partial slots along j
#define EPSQ 1e-20f

// butterfly sum over lane bits 0..3 (the 16 c-lanes), pure VALU via DPP
template<int CTRL>
__device__ __forceinline__ float dpp_add(float v) {
    int s = __builtin_amdgcn_update_dpp(0, __float_as_int(v), CTRL, 0xF, 0xF, true);
    return v + __int_as_float(s);
}
__device__ __forceinline__ float red16(float v) {
    v = dpp_add<0xB1>(v);    // quad_perm xor1
    v = dpp_add<0x4E>(v);    // quad_perm xor2
    v = dpp_add<0x141>(v);   // row_half_mirror (pairs quads)
    v = dpp_add<0x140>(v);   // row_mirror (pairs half-rows)
    return v;
}

// One routing iteration, barrier-free b-loop.
// Thread (j, c) holds W[j, :, n*16+c] for ALL n -> softmax is thread-local.
// Linearity trick: logits b_r[b,j,n] = u . (v0+...+v_{r-1}) -> carry only vsum.
template<int R>
__global__ __launch_bounds__(NTH, 3)
void rout_kernel(const float* __restrict__ x, const float* __restrict__ W,
                 const float* __restrict__ vsum, float* __restrict__ part) {
    __shared__ float xs[BB][JT][8];    // 4 KB
    __shared__ float sacc[BB][KK];     // 5 KB block accumulator

    const int t  = threadIdx.x;
    const int c  = t & 15;             // lane bits 0..3
    const int jr = t >> 4;             // 0..15 (bits 4,5 = jr&3 within wave)
    const int jx = blockIdx.x;
    const int bg = blockIdx.y;
    const int j  = jx * JT + jr;
    const int b0 = bg * BB;

    // ---- W -> registers: w[i][n] = W[j, i, n*16+c]  (80 VGPR) ----
    float w[8][NC];
    {
        const float* wp = W + (size_t)j * (8 * KK) + c;
        #pragma unroll
        for (int i = 0; i < 8; ++i)
            #pragma unroll
            for (int n = 0; n < NC; ++n)
                w[i][n] = wp[i * KK + n * CL];
    }
    // ---- stage x tile (8 b x 16 j x 8 i), zero sacc ----
    {
        const int bb = t >> 5, rem = t & 31, jj = rem >> 1, hf = rem & 1;
        *(float4*)&xs[bb][jj][hf * 4] =
            *(const float4*)(x + ((size_t)(b0 + bb) * NJ + jx * JT + jj) * 8 + hf * 4);
    }
    for (int e = t; e < BB * KK; e += NTH) ((float*)sacc)[e] = 0.f;
    __syncthreads();

    #pragma unroll 1
    for (int bb = 0; bb < BB; ++bb) {
        // x row for this j (broadcast across the 16 c-lanes)
        float xi[8];
        #pragma unroll
        for (int i = 0; i < 8; i += 2) {
            const float2 xv = *(const float2*)&xs[bb][jr][i];
            xi[i] = xv.x; xi[i + 1] = xv.y;
        }
        // vsum slice for this (b, c): 10 dwords, L2-hot
        float vs[NC];
        if (R > 0) {
            const float* vp = vsum + (size_t)(b0 + bb) * KK + c;
            #pragma unroll
            for (int n = 0; n < NC; ++n) vs[n] = vp[n * CL];
        }
        // u[n] = sum_i x[i] * W[i][n]   (80 FMA, 10 independent chains)
        float u[NC];
        #pragma unroll
        for (int n = 0; n < NC; ++n) {
            float a = 0.f;
            #pragma unroll
            for (int i = 0; i < 8; ++i) a = fmaf(w[i][n], xi[i], a);
            u[n] = a;
        }
        // routing weights
        float cw[NC];
        if (R > 0) {
            float lg[NC];
            #pragma unroll
            for (int n = 0; n < NC; ++n) lg[n] = red16(u[n] * vs[n]);
            float m = lg[0];
            #pragma unroll
            for (int n = 1; n < NC; ++n) m = fmaxf(m, lg[n]);
            float sum = 0.f;
            #pragma unroll
            for (int n = 0; n < NC; ++n) { lg[n] = __expf(lg[n] - m); sum += lg[n]; }
            const float inv = 1.f / sum;
            #pragma unroll
            for (int n = 0; n < NC; ++n) cw[n] = lg[n] * inv;
        } else {
            #pragma unroll
            for (int n = 0; n < NC; ++n) cw[n] = 0.1f;
        }
        // accumulate s partial into LDS (4-way same-address within wave: cheap)
        #pragma unroll
        for (int n = 0; n < NC; ++n)
            atomicAdd(&sacc[bb][n * CL + c], cw[n] * u[n]);
    }
    __syncthreads();

    // ---- block partial -> global (coalesced) ----
    for (int e = t; e < BB * KK; e += NTH)
        part[((size_t)jx * NB + b0) * KK + e] = ((float*)sacc)[e];
}

// Sum NPART partials (coalesced), +bias, squash.
// MODE: 0 vsum=v, 1 vsum+=v, 2 out=v. Grid: 20 blocks x 1024 threads.
template<int MODE>
__global__ __launch_bounds__(1024)
void reduce_squash(const float* __restrict__ part, const float* __restrict__ biases,
                   float* __restrict__ vsum, float* __restrict__ out) {
    __shared__ float4 red[16][64];     // 16 KB
    const int t   = threadIdx.x;
    const int col = t & 63;            // f4-column within block
    const int pc  = t >> 6;            // 16 partial-chunks of 32
    const int g   = blockIdx.x * 64 + col;   // global f4 index, 0..1279
    const float4* p4 = (const float4*)part;

    float4 acc = {0.f, 0.f, 0.f, 0.f};
    #pragma unroll 4
    for (int p = pc * 32; p < pc * 32 + 32; ++p) {
        const float4 v = p4[(size_t)p * (NB * KK / 4) + g];
        acc.x += v.x; acc.y += v.y; acc.z += v.z; acc.w += v.w;
    }
    red[pc][col] = acc;
    __syncthreads();
    if (pc == 0) {
        #pragma unroll
        for (int q = 1; q < 16; ++q) {
            const float4 v = red[q][col];
            acc.x += v.x; acc.y += v.y; acc.z += v.z; acc.w += v.w;
        }
        const int k4 = g % 40;
        const float4 bb = *(const float4*)(biases + k4 * 4);
        float4 v;
        {
            const float s0 = acc.x + bb.x, n0 = fabsf(s0);
            v.x = (n0 * n0) / (1.f + n0 * n0) / (n0 + EPSQ) * s0;
            const float s1 = acc.y + bb.y, n1 = fabsf(s1);
            v.y = (n1 * n1) / (1.f + n1 * n1) / (n1 + EPSQ) * s1;
            const float s2 = acc.z + bb.z, n2 = fabsf(s2);
            v.z = (n2 * n2) / (1.f + n2 * n2) / (n2 + EPSQ) * s2;
            const float s3 = acc.w + bb.w, n3 = fabsf(s3);
            v.w = (n3 * n3) / (1.f + n3 * n3) / (n3 + EPSQ) * s3;
        }
        if (MODE == 2) {
            ((float4*)out)[g] = v;
        } else if (MODE == 1) {
            float4 o = ((float4*)vsum)[g];
            o.x += v.x; o.y += v.y; o.z += v.z; o.w += v.w;
            ((float4*)vsum)[g] = o;
        } else {
            ((float4*)vsum)[g] = v;
        }
    }
}

extern "C" void kernel_launch(void* const* d_in, const int* in_sizes, int n_in,
                              void* d_out, int out_size, void* d_ws, size_t ws_size,
                              hipStream_t stream) {
    const float* x      = (const float*)d_in[0];
    const float* W      = (const float*)d_in[1];
    const float* biases = (const float*)d_in[2];
    float* out  = (float*)d_out;
    float* part = (float*)d_ws;                        // [NPART][NB*KK]
    float* vsum = part + (size_t)NPART * NB * KK;      // [NB*KK]

    const dim3 grid(NJ / JT, NB / BB);   // 512 x 4 = 2048 blocks

    rout_kernel<0><<<grid, NTH, 0, stream>>>(x, W, nullptr, part);
    reduce_squash<0><<<20, 1024, 0, stream>>>(part, biases, vsum, out);

    rout_kernel<1><<<grid, NTH, 0, stream>>>(x, W, vsum, part);
    reduce_squash<1><<<20, 1024, 0, stream>>>(part, biases, vsum, out);

    rout_kernel<2><<<grid, NTH, 0, stream>>>(x, W, vsum, part);
    reduce_squash<2><<<20, 1024, 0, stream>>>(part, biases, vsum, out);
}

// Round 6
// 147.943 us; speedup vs baseline: 4.5479x; 4.5479x over previous
//
#include <hip/hip_runtime.h>

#define NB 32      // batch
#define NJ 8192    // h*w*Nin
#define NC 10      // NUM_CAPS
#define CL 16      // CAP_LEN
#define KK 160     // NC*CL
#define JT 16      // j per block
#define NTHR 640   // 40 k4 x 16 jj  (t = k4*16 + jj)
#define BB 16      // batches per block (grid.y = NB/BB = 2)
#define BCH 4      // batches per barrier pair
#define NPART (NJ / JT)   // 512 partial slots along j
#define EPSQ 1e-20f

// in-wave sum over jj = lane&15, pure VALU via DPP adds
template<int CTRL>
__device__ __forceinline__ float dpp_add(float v) {
    int s = __builtin_amdgcn_update_dpp(0, __float_as_int(v), CTRL, 0xF, 0xF, true);
    return v + __int_as_float(s);
}
__device__ __forceinline__ float red16(float v) {
    v = dpp_add<0xB1>(v);    // quad_perm xor1
    v = dpp_add<0x4E>(v);    // quad_perm xor2
    v = dpp_add<0x141>(v);   // row_half_mirror
    v = dpp_add<0x140>(v);   // row_mirror
    return v;
}

// One routing iteration. W in registers (32 VGPR), u in registers,
// j-reduce via DPP, partials stored (no global atomics).
// Linearity trick: logits b_r[b,j,n] = u . (v0+...+v_{r-1}) -> carry only vsum.
template<int R>
__global__ __launch_bounds__(NTHR, 5)
void rout_kernel(const float* __restrict__ x, const float* __restrict__ W,
                 const float* __restrict__ vsum, float* __restrict__ part) {
    __shared__ float xs[BB][JT][10];   // 10 KB, pad -> b64 reads conflict-free
    __shared__ float bl[BCH][JT][12];  // 3 KB
    __shared__ float cl[BCH][JT][12];  // 3 KB

    const int t   = threadIdx.x;
    const int jj  = t & 15;            // j within tile
    const int k4  = t >> 4;            // float4 chunk of k, 0..39
    const int nB  = k4 >> 2;           // cap index
    const int c4  = k4 & 3;            // c-quad within cap (lane bits 4,5)
    const int j0  = blockIdx.x * JT;
    const int bof = blockIdx.y * BB;   // batch offset of this block

    // ---- W -> registers, once (proven 32-VGPR layout) ----
    float4 w[8];
    {
        const float* wp = W + ((size_t)(j0 + jj) * 8) * KK + (k4 << 2);
        #pragma unroll
        for (int i = 0; i < 8; ++i)
            w[i] = *(const float4*)(wp + i * KK);
    }
    // ---- x tile (BB batches) -> LDS ----
    for (int e4 = t; e4 < BB * JT * 2; e4 += NTHR) {
        const int bb = e4 >> 5, rem = e4 & 31, jx = rem >> 1, hf = rem & 1;
        const float4 v = *(const float4*)(x + ((size_t)(bof + bb) * NJ + j0 + jx) * 8 + hf * 4);
        float* d = &xs[bb][jx][hf * 4];
        d[0] = v.x; d[1] = v.y; d[2] = v.z; d[3] = v.w;
    }
    __syncthreads();

    for (int b0 = 0; b0 < BB; b0 += BCH) {
        // ---- A: u quads in registers ----
        float4 u[BCH];
        #pragma unroll
        for (int bc = 0; bc < BCH; ++bc) {
            float4 acc = {0.f, 0.f, 0.f, 0.f};
            #pragma unroll
            for (int seg = 0; seg < 4; ++seg) {
                const float2 xv = *(const float2*)&xs[b0 + bc][jj][seg * 2];
                const float4 wa = w[seg * 2], wb = w[seg * 2 + 1];
                acc.x = fmaf(wa.x, xv.x, acc.x); acc.y = fmaf(wa.y, xv.x, acc.y);
                acc.z = fmaf(wa.z, xv.x, acc.z); acc.w = fmaf(wa.w, xv.x, acc.w);
                acc.x = fmaf(wb.x, xv.y, acc.x); acc.y = fmaf(wb.y, xv.y, acc.y);
                acc.z = fmaf(wb.z, xv.y, acc.z); acc.w = fmaf(wb.w, xv.y, acc.w);
            }
            u[bc] = acc;
        }

        if (R > 0) {
            // ---- B: logit = u . vsum (vsum direct from global: L1-hot,
            //         16-lane-uniform addresses), reduce over c4 ----
            #pragma unroll
            for (int bc = 0; bc < BCH; ++bc) {
                const int b = bof + b0 + bc;
                const float4 vv = *(const float4*)(vsum + (size_t)b * KK + (k4 << 2));
                float bd = u[bc].x * vv.x + u[bc].y * vv.y
                         + u[bc].z * vv.z + u[bc].w * vv.w;
                bd += __shfl_xor(bd, 16);
                bd += __shfl_xor(bd, 32);
                if (c4 == 0) bl[bc][jj][nB] = bd;
            }
            __syncthreads();
            // ---- C: softmax over n, 640 = 4bc x 16jj x 10nn threads ----
            {
                const int bcC = t / 160, rem = t % 160;
                const int jjC = rem & 15, nn = rem >> 4;
                float m = -1e30f;
                #pragma unroll
                for (int q = 0; q < NC; ++q) m = fmaxf(m, bl[bcC][jjC][q]);
                float sum = 0.f;
                #pragma unroll
                for (int q = 0; q < NC; ++q) sum += __expf(bl[bcC][jjC][q] - m);
                cl[bcC][jjC][nn] = __expf(bl[bcC][jjC][nn] - m) / sum;
            }
            __syncthreads();
        }

        // ---- D: s partial = sum_jj c*u via DPP, one f4 store per (b,k4) ----
        #pragma unroll
        for (int bc = 0; bc < BCH; ++bc) {
            const int b = bof + b0 + bc;
            const float c = (R == 0) ? 0.1f : cl[bc][jj][nB];
            const float sx = red16(u[bc].x * c);
            const float sy = red16(u[bc].y * c);
            const float sz = red16(u[bc].z * c);
            const float sw = red16(u[bc].w * c);
            if (jj == 0) {
                float4 q; q.x = sx; q.y = sy; q.z = sz; q.w = sw;
                *(float4*)(part + ((size_t)blockIdx.x * NB + b) * KK + (k4 << 2)) = q;
            }
        }
    }
}

// Sum NPART partials (coalesced), +bias, squash.
// MODE: 0 vsum=v, 1 vsum+=v, 2 out=v. Grid: 20 blocks x 1024 threads.
template<int MODE>
__global__ __launch_bounds__(1024)
void reduce_squash(const float* __restrict__ part, const float* __restrict__ biases,
                   float* __restrict__ vsum, float* __restrict__ out) {
    __shared__ float4 red[16][64];     // 16 KB
    const int t   = threadIdx.x;
    const int col = t & 63;            // f4-column within block
    const int pc  = t >> 6;            // 16 partial-chunks of 32
    const int g   = blockIdx.x * 64 + col;   // global f4 index, 0..1279
    const float4* p4 = (const float4*)part;

    float4 acc = {0.f, 0.f, 0.f, 0.f};
    #pragma unroll 4
    for (int p = pc * 32; p < pc * 32 + 32; ++p) {
        const float4 v = p4[(size_t)p * (NB * KK / 4) + g];
        acc.x += v.x; acc.y += v.y; acc.z += v.z; acc.w += v.w;
    }
    red[pc][col] = acc;
    __syncthreads();
    if (pc == 0) {
        #pragma unroll
        for (int q = 1; q < 16; ++q) {
            const float4 v = red[q][col];
            acc.x += v.x; acc.y += v.y; acc.z += v.z; acc.w += v.w;
        }
        const int k4 = g % 40;
        const float4 bb = *(const float4*)(biases + k4 * 4);
        float4 v;
        {
            const float s0 = acc.x + bb.x, n0 = fabsf(s0);
            v.x = (n0 * n0) / (1.f + n0 * n0) / (n0 + EPSQ) * s0;
            const float s1 = acc.y + bb.y, n1 = fabsf(s1);
            v.y = (n1 * n1) / (1.f + n1 * n1) / (n1 + EPSQ) * s1;
            const float s2 = acc.z + bb.z, n2 = fabsf(s2);
            v.z = (n2 * n2) / (1.f + n2 * n2) / (n2 + EPSQ) * s2;
            const float s3 = acc.w + bb.w, n3 = fabsf(s3);
            v.w = (n3 * n3) / (1.f + n3 * n3) / (n3 + EPSQ) * s3;
        }
        if (MODE == 2) {
            ((float4*)out)[g] = v;
        } else if (MODE == 1) {
            float4 o = ((float4*)vsum)[g];
            o.x += v.x; o.y += v.y; o.z += v.z; o.w += v.w;
            ((float4*)vsum)[g] = o;
        } else {
            ((float4*)vsum)[g] = v;
        }
    }
}

extern "C" void kernel_launch(void* const* d_in, const int* in_sizes, int n_in,
                              void* d_out, int out_size, void* d_ws, size_t ws_size,
                              hipStream_t stream) {
    const float* x      = (const float*)d_in[0];
    const float* W      = (const float*)d_in[1];
    const float* biases = (const float*)d_in[2];
    float* out  = (float*)d_out;
    float* part = (float*)d_ws;                        // [NPART][NB*KK]
    float* vsum = part + (size_t)NPART * NB * KK;      // [NB*KK]

    const dim3 grid(NJ / JT, NB / BB);   // 512 x 2 = 1024 blocks (4/CU)

    rout_kernel<0><<<grid, NTHR, 0, stream>>>(x, W, nullptr, part);
    reduce_squash<0><<<20, 1024, 0, stream>>>(part, biases, vsum, out);

    rout_kernel<1><<<grid, NTHR, 0, stream>>>(x, W, vsum, part);
    reduce_squash<1><<<20, 1024, 0, stream>>>(part, biases, vsum, out);

    rout_kernel<2><<<grid, NTHR, 0, stream>>>(x, W, vsum, part);
    reduce_squash<2><<<20, 1024, 0, stream>>>(part, biases, vsum, out);
}

// Round 7
// 139.480 us; speedup vs baseline: 4.8238x; 1.0607x over previous
//
#include <hip/hip_runtime.h>

#define NB 32      // batch
#define NJ 8192    // h*w*Nin
#define NC 10      // NUM_CAPS
#define CL 16      // CAP_LEN
#define KK 160     // NC*CL
#define JT 16      // j per block
#define NTHR 640   // 40 k4 x 16 jj  (t = k4*16 + jj)
#define BCH 4      // batches per barrier pair
#define NPART (NJ / JT)   // 512 partial slots along j
#define EPSQ 1e-20f

// in-wave sum over jj = lane&15, pure VALU via DPP adds
template<int CTRL>
__device__ __forceinline__ float dpp_add(float v) {
    int s = __builtin_amdgcn_update_dpp(0, __float_as_int(v), CTRL, 0xF, 0xF, true);
    return v + __int_as_float(s);
}
__device__ __forceinline__ float red16(float v) {
    v = dpp_add<0xB1>(v);    // quad_perm xor1
    v = dpp_add<0x4E>(v);    // quad_perm xor2
    v = dpp_add<0x141>(v);   // row_half_mirror
    v = dpp_add<0x140>(v);   // row_mirror
    return v;
}

// W[j][i][k] -> Wt[(jx*8+i)*640 + t] where t = k4*16 + jj encodes (jj,k4).
// Makes the rout kernel's per-thread W loads lane-consecutive (coalesced).
// Block (jx, ih): 16 j-rows x 4 i-slices. Read coalesced, write coalesced.
__global__ __launch_bounds__(NTHR)
void transpose_w(const float* __restrict__ W, float* __restrict__ Wt) {
    __shared__ float4 lds[16 * 165];   // jj*165 + q*41 + k4 ; 42.2 KB, ~2-way banks
    const int t  = threadIdx.x;
    const int jx = blockIdx.x, ih = blockIdx.y;
    const float4* W4 = (const float4*)W;
    float4* Wt4 = (float4*)Wt;

    {
        const int jj = t / 40, col = t % 40;     // read: lanes consecutive in col
        #pragma unroll
        for (int q = 0; q < 4; ++q)
            lds[jj * 165 + q * 41 + col] =
                W4[((size_t)(jx * 16 + jj)) * 320 + (ih * 4 + q) * 40 + col];
    }
    __syncthreads();
    {
        const int jj = t & 15, k4 = t >> 4;      // write: lanes consecutive in t
        #pragma unroll
        for (int q = 0; q < 4; ++q)
            Wt4[((size_t)jx * 8 + ih * 4 + q) * 640 + t] =
                lds[jj * 165 + q * 41 + k4];
    }
}

// One routing iteration (round-4 structure). W in registers, u in registers,
// j-reduce via DPP, partials stored (no global atomics).
// TR: load W from transposed Wt (coalesced) vs original W (fallback).
// Linearity trick: logits b_r[b,j,n] = u . (v0+...+v_{r-1}) -> carry only vsum.
template<int R, bool TR>
__global__ __launch_bounds__(NTHR, 5)
void rout_kernel(const float* __restrict__ x, const float* __restrict__ Wp,
                 const float* __restrict__ vsum, float* __restrict__ part) {
    __shared__ float xs[NB][JT][10];   // 20 KB, pad -> b64 reads conflict-free
    __shared__ float vsl[NB][KK];      // 20 KB
    __shared__ float bl[BCH][JT][12];
    __shared__ float cl[BCH][JT][12];

    const int t   = threadIdx.x;
    const int jj  = t & 15;            // j within tile
    const int k4  = t >> 4;            // float4 chunk of k, 0..39
    const int nB  = k4 >> 2;           // cap index
    const int c4  = k4 & 3;            // c-quad within cap (lane bits 4,5)
    const int j0  = blockIdx.x * JT;

    // ---- W -> registers, once ----
    float4 w[8];
    if (TR) {
        const float4* wt = (const float4*)Wp + (size_t)blockIdx.x * 8 * 640 + t;
        #pragma unroll
        for (int i = 0; i < 8; ++i)
            w[i] = wt[i * 640];        // lane-consecutive: 1 KB / wave-inst
    } else {
        const float* wp = Wp + ((size_t)(j0 + jj) * 8) * KK + (k4 << 2);
        #pragma unroll
        for (int i = 0; i < 8; ++i)
            w[i] = *(const float4*)(wp + i * KK);
    }
    // ---- x tile -> LDS ----
    for (int e4 = t; e4 < NB * JT * 2; e4 += NTHR) {
        const int b = e4 >> 5, rem = e4 & 31, jx = rem >> 1, hf = rem & 1;
        const float4 v = *(const float4*)(x + ((size_t)b * NJ + j0 + jx) * 8 + hf * 4);
        float* d = &xs[b][jx][hf * 4];
        d[0] = v.x; d[1] = v.y; d[2] = v.z; d[3] = v.w;
    }
    // ---- vsum -> LDS (R>0) ----
    if (R > 0) {
        for (int f4 = t; f4 < NB * 40; f4 += NTHR) {
            const int b = f4 / 40, rem = f4 % 40;
            *(float4*)&vsl[b][rem * 4] = *(const float4*)(vsum + (size_t)b * KK + rem * 4);
        }
    }
    __syncthreads();

    for (int b0 = 0; b0 < NB; b0 += BCH) {
        // ---- A: u quads in registers ----
        float4 u[BCH];
        #pragma unroll
        for (int bc = 0; bc < BCH; ++bc) {
            float4 acc = {0.f, 0.f, 0.f, 0.f};
            #pragma unroll
            for (int seg = 0; seg < 4; ++seg) {
                const float2 xv = *(const float2*)&xs[b0 + bc][jj][seg * 2];
                const float4 wa = w[seg * 2], wb = w[seg * 2 + 1];
                acc.x = fmaf(wa.x, xv.x, acc.x); acc.y = fmaf(wa.y, xv.x, acc.y);
                acc.z = fmaf(wa.z, xv.x, acc.z); acc.w = fmaf(wa.w, xv.x, acc.w);
                acc.x = fmaf(wb.x, xv.y, acc.x); acc.y = fmaf(wb.y, xv.y, acc.y);
                acc.z = fmaf(wb.z, xv.y, acc.z); acc.w = fmaf(wb.w, xv.y, acc.w);
            }
            u[bc] = acc;
        }

        if (R > 0) {
            // ---- B: logit = u . vsum, reduce over c4 ----
            #pragma unroll
            for (int bc = 0; bc < BCH; ++bc) {
                const float4 vv = *(const float4*)&vsl[b0 + bc][k4 * 4];
                float bd = u[bc].x * vv.x + u[bc].y * vv.y
                         + u[bc].z * vv.z + u[bc].w * vv.w;
                bd += __shfl_xor(bd, 16);
                bd += __shfl_xor(bd, 32);
                if (c4 == 0) bl[bc][jj][nB] = bd;
            }
            __syncthreads();
            // ---- C: softmax over n, 640 = 4bc x 16jj x 10nn threads ----
            {
                const int bcC = t / 160, rem = t % 160;
                const int jjC = rem & 15, nn = rem >> 4;
                float m = -1e30f;
                #pragma unroll
                for (int q = 0; q < NC; ++q) m = fmaxf(m, bl[bcC][jjC][q]);
                float sum = 0.f;
                #pragma unroll
                for (int q = 0; q < NC; ++q) sum += __expf(bl[bcC][jjC][q] - m);
                cl[bcC][jjC][nn] = __expf(bl[bcC][jjC][nn] - m) / sum;
            }
            __syncthreads();
        }

        // ---- D: s partial = sum_jj c*u via DPP, one f4 store per (b,k4) ----
        #pragma unroll
        for (int bc = 0; bc < BCH; ++bc) {
            const int b = b0 + bc;
            const float c = (R == 0) ? 0.1f : cl[bc][jj][nB];
            const float sx = red16(u[bc].x * c);
            const float sy = red16(u[bc].y * c);
            const float sz = red16(u[bc].z * c);
            const float sw = red16(u[bc].w * c);
            if (jj == 0) {
                float4 q; q.x = sx; q.y = sy; q.z = sz; q.w = sw;
                *(float4*)(part + ((size_t)blockIdx.x * NB + b) * KK + (k4 << 2)) = q;
            }
        }
    }
}

// Sum NPART partials (coalesced), +bias, squash.
// MODE: 0 vsum=v, 1 vsum+=v, 2 out=v. Grid: 20 blocks x 1024 threads.
template<int MODE>
__global__ __launch_bounds__(1024)
void reduce_squash(const float* __restrict__ part, const float* __restrict__ biases,
                   float* __restrict__ vsum, float* __restrict__ out) {
    __shared__ float4 red[16][64];     // 16 KB
    const int t   = threadIdx.x;
    const int col = t & 63;
    const int pc  = t >> 6;
    const int g   = blockIdx.x * 64 + col;   // global f4 index, 0..1279
    const float4* p4 = (const float4*)part;

    float4 acc = {0.f, 0.f, 0.f, 0.f};
    #pragma unroll 4
    for (int p = pc * 32; p < pc * 32 + 32; ++p) {
        const float4 v = p4[(size_t)p * (NB * KK / 4) + g];
        acc.x += v.x; acc.y += v.y; acc.z += v.z; acc.w += v.w;
    }
    red[pc][col] = acc;
    __syncthreads();
    if (pc == 0) {
        #pragma unroll
        for (int q = 1; q < 16; ++q) {
            const float4 v = red[q][col];
            acc.x += v.x; acc.y += v.y; acc.z += v.z; acc.w += v.w;
        }
        const int k4 = g % 40;
        const float4 bb = *(const float4*)(biases + k4 * 4);
        float4 v;
        {
            const float s0 = acc.x + bb.x, n0 = fabsf(s0);
            v.x = (n0 * n0) / (1.f + n0 * n0) / (n0 + EPSQ) * s0;
            const float s1 = acc.y + bb.y, n1 = fabsf(s1);
            v.y = (n1 * n1) / (1.f + n1 * n1) / (n1 + EPSQ) * s1;
            const float s2 = acc.z + bb.z, n2 = fabsf(s2);
            v.z = (n2 * n2) / (1.f + n2 * n2) / (n2 + EPSQ) * s2;
            const float s3 = acc.w + bb.w, n3 = fabsf(s3);
            v.w = (n3 * n3) / (1.f + n3 * n3) / (n3 + EPSQ) * s3;
        }
        if (MODE == 2) {
            ((float4*)out)[g] = v;
        } else if (MODE == 1) {
            float4 o = ((float4*)vsum)[g];
            o.x += v.x; o.y += v.y; o.z += v.z; o.w += v.w;
            ((float4*)vsum)[g] = o;
        } else {
            ((float4*)vsum)[g] = v;
        }
    }
}

extern "C" void kernel_launch(void* const* d_in, const int* in_sizes, int n_in,
                              void* d_out, int out_size, void* d_ws, size_t ws_size,
                              hipStream_t stream) {
    const float* x      = (const float*)d_in[0];
    const float* W      = (const float*)d_in[1];
    const float* biases = (const float*)d_in[2];
    float* out = (float*)d_out;

    const size_t wt_f  = (size_t)NJ * 8 * KK;          // 10.49 M floats (41.9 MB)
    const size_t need  = (wt_f + (size_t)NPART * NB * KK + NB * KK) * sizeof(float);
    const dim3 grid(NJ / JT);   // 512 blocks

    if (ws_size >= need) {
        float* Wt   = (float*)d_ws;
        float* part = Wt + wt_f;                       // [NPART][NB*KK]
        float* vsum = part + (size_t)NPART * NB * KK;  // [NB*KK]

        transpose_w<<<dim3(NJ / JT, 2), NTHR, 0, stream>>>(W, Wt);

        rout_kernel<0, true><<<grid, NTHR, 0, stream>>>(x, Wt, nullptr, part);
        reduce_squash<0><<<20, 1024, 0, stream>>>(part, biases, vsum, out);

        rout_kernel<1, true><<<grid, NTHR, 0, stream>>>(x, Wt, vsum, part);
        reduce_squash<1><<<20, 1024, 0, stream>>>(part, biases, vsum, out);

        rout_kernel<2, true><<<grid, NTHR, 0, stream>>>(x, Wt, vsum, part);
        reduce_squash<2><<<20, 1024, 0, stream>>>(part, biases, vsum, out);
    } else {
        float* part = (float*)d_ws;                    // round-4 fallback
        float* vsum = part + (size_t)NPART * NB * KK;

        rout_kernel<0, false><<<grid, NTHR, 0, stream>>>(x, W, nullptr, part);
        reduce_squash<0><<<20, 1024, 0, stream>>>(part, biases, vsum, out);

        rout_kernel<1, false><<<grid, NTHR, 0, stream>>>(x, W, vsum, part);
        reduce_squash<1><<<20, 1024, 0, stream>>>(part, biases, vsum, out);

        rout_kernel<2, false><<<grid, NTHR, 0, stream>>>(x, W, vsum, part);
        reduce_squash<2><<<20, 1024, 0, stream>>>(part, biases, vsum, out);
    }
}